// Round 2
// baseline (18335.904 us; speedup 1.0000x reference)
//
#include <hip/hip_runtime.h>
#include <hip/hip_fp16.h>

// ============================================================================
// ATTNAligner forward: conv prenet -> 3x BiLSTM stacks -> CTC + mel heads
// B=16, T=1000, MEL=80, H=512, H2=256, VOCAB=80, K=5, L=2
//
// Workspace layout (floats), total ~251 MiB.
// ============================================================================

typedef unsigned int u32;
typedef _Float16 h2_t __attribute__((ext_vector_type(2)));
union U32H2 { u32 u; h2_t h; };

#define T_LEN 1000
#define BATCH 16
#define SROWS (T_LEN * BATCH)

__device__ __forceinline__ float dot2f(u32 a, u32 b, float c) {
#if __has_builtin(__builtin_amdgcn_fdot2)
    U32H2 ua; ua.u = a; U32H2 ub; ub.u = b;
    return __builtin_amdgcn_fdot2(ua.h, ub.h, c, false);
#else
    U32H2 ua; ua.u = a; U32H2 ub; ub.u = b;
    return c + (float)ua.h.x * (float)ub.h.x + (float)ua.h.y * (float)ub.h.y;
#endif
}

__device__ __forceinline__ u32 pack2h(float a, float b) {
    h2_t p; p.x = (_Float16)a; p.y = (_Float16)b;
    U32H2 u; u.h = p; return u.u;
}

__device__ __forceinline__ float fsigm(float x) { return 1.0f / (1.0f + __expf(-x)); }
__device__ __forceinline__ float ftanh_(float x) {
    x = fminf(fmaxf(x, -15.0f), 15.0f);
    float e = __expf(-2.0f * x);
    return (1.0f - e) / (1.0f + e);
}

// ---------------------------------------------------------------------------
// Generic transpose: src[R][C] -> dst[C][R]
// ---------------------------------------------------------------------------
__global__ void transpose_kernel(const float* __restrict__ src, float* __restrict__ dst,
                                 int R, int C) {
    int total = R * C;
    for (int i = blockIdx.x * blockDim.x + threadIdx.x; i < total; i += gridDim.x * blockDim.x) {
        int r = i / C, c = i - r * C;
        dst[(size_t)c * R + r] = src[i];
    }
}

// ---------------------------------------------------------------------------
// Pack recurrent weights Whh [layers][2][1024][256] f32
//   -> wp [layers][2][32 g][1024 j][4 q] u32, u32 = half2(W[j][8g+2q], W[j][8g+2q+1])
// ---------------------------------------------------------------------------
__global__ void prep_whh_kernel(const float* __restrict__ whh, u32* __restrict__ wp, int total) {
    for (int idx = blockIdx.x * blockDim.x + threadIdx.x; idx < total; idx += gridDim.x * blockDim.x) {
        int q = idx & 3;
        int j = (idx >> 2) & 1023;
        int g = (idx >> 12) & 31;
        int d = (idx >> 17) & 1;
        int l = idx >> 18;
        int k = g * 8 + q * 2;
        const float* s = whh + ((size_t)(l * 2 + d) * 1024 + j) * 256 + k;
        wp[idx] = pack2h(s[0], s[1]);
    }
}

// ---------------------------------------------------------------------------
// Conv1: mels [B][80][T] (normalized inline) -> y1 [B][512][T], causal K=5 + BN
// ---------------------------------------------------------------------------
__global__ __launch_bounds__(256) void conv1_kernel(
    const float* __restrict__ mels, const float* __restrict__ w,
    const float* __restrict__ cbias, const float* __restrict__ bg,
    const float* __restrict__ bb, const float* __restrict__ bm,
    const float* __restrict__ bv, float* __restrict__ y1)
{
    __shared__ float xin[80 * 72];
    int t0 = blockIdx.x * 64;
    int b = blockIdx.y;
    int tid = threadIdx.x;
    for (int idx = tid; idx < 80 * 68; idx += 256) {
        int m = idx / 68, i = idx - m * 68;
        int t = t0 - 4 + i;
        float v = 0.0f;
        if (t >= 0 && t < T_LEN) v = mels[(size_t)(b * 80 + m) * T_LEN + t] * (1.0f / 6.0f) + 1.0f;
        xin[m * 72 + i] = v;
    }
    __syncthreads();
    int tg = tid & 15, cl = tid >> 4;
    for (int pass = 0; pass < 32; ++pass) {
        int c = pass * 16 + cl;
        const float* wc = w + (size_t)c * 400;
        float a0 = 0, a1 = 0, a2 = 0, a3 = 0;
        for (int m = 0; m < 80; ++m) {
            float4 xa = *(const float4*)&xin[m * 72 + tg * 4];
            float4 xb = *(const float4*)&xin[m * 72 + tg * 4 + 4];
            float w0 = wc[m * 5 + 0], w1 = wc[m * 5 + 1], w2 = wc[m * 5 + 2];
            float w3 = wc[m * 5 + 3], w4 = wc[m * 5 + 4];
            a0 += w0 * xa.x + w1 * xa.y + w2 * xa.z + w3 * xa.w + w4 * xb.x;
            a1 += w0 * xa.y + w1 * xa.z + w2 * xa.w + w3 * xb.x + w4 * xb.y;
            a2 += w0 * xa.z + w1 * xa.w + w2 * xb.x + w3 * xb.y + w4 * xb.z;
            a3 += w0 * xa.w + w1 * xb.x + w2 * xb.y + w3 * xb.z + w4 * xb.w;
        }
        float scale = bg[c] * rsqrtf(bv[c] + 1e-5f);
        float shift = (cbias[c] - bm[c]) * scale + bb[c];
        int tb = t0 + tg * 4;
        float* yp = y1 + (size_t)(b * 512 + c) * T_LEN + tb;
        if (tb + 0 < T_LEN) yp[0] = a0 * scale + shift;
        if (tb + 1 < T_LEN) yp[1] = a1 * scale + shift;
        if (tb + 2 < T_LEN) yp[2] = a2 * scale + shift;
        if (tb + 3 < T_LEN) yp[3] = a3 * scale + shift;
    }
}

// ---------------------------------------------------------------------------
// Conv2: y1 [B][512][T] -> xs [T*B][512] (row = t*B+b), causal K=5 + BN
// dynamic LDS 512*72*4 = 147456 B
// ---------------------------------------------------------------------------
__global__ __launch_bounds__(256) void conv2_kernel(
    const float* __restrict__ y1, const float* __restrict__ w,
    const float* __restrict__ cbias, const float* __restrict__ bg,
    const float* __restrict__ bb, const float* __restrict__ bm,
    const float* __restrict__ bv, float* __restrict__ xs)
{
    extern __shared__ float xin[]; // [512][72]
    int t0 = blockIdx.x * 64;
    int b = blockIdx.y;
    int tid = threadIdx.x;
    for (int idx = tid; idx < 512 * 68; idx += 256) {
        int m = idx / 68, i = idx - m * 68;
        int t = t0 - 4 + i;
        float v = 0.0f;
        if (t >= 0 && t < T_LEN) v = y1[(size_t)(b * 512 + m) * T_LEN + t];
        xin[m * 72 + i] = v;
    }
    __syncthreads();
    int tg = tid & 15, cl = tid >> 4;
    for (int pass = 0; pass < 32; ++pass) {
        int c = pass * 16 + cl;
        const float* wc = w + (size_t)c * 2560;
        float a0 = 0, a1 = 0, a2 = 0, a3 = 0;
        for (int m = 0; m < 512; ++m) {
            float4 xa = *(const float4*)&xin[m * 72 + tg * 4];
            float4 xb = *(const float4*)&xin[m * 72 + tg * 4 + 4];
            float w0 = wc[m * 5 + 0], w1 = wc[m * 5 + 1], w2 = wc[m * 5 + 2];
            float w3 = wc[m * 5 + 3], w4 = wc[m * 5 + 4];
            a0 += w0 * xa.x + w1 * xa.y + w2 * xa.z + w3 * xa.w + w4 * xb.x;
            a1 += w0 * xa.y + w1 * xa.z + w2 * xa.w + w3 * xb.x + w4 * xb.y;
            a2 += w0 * xa.z + w1 * xa.w + w2 * xb.x + w3 * xb.y + w4 * xb.z;
            a3 += w0 * xa.w + w1 * xb.x + w2 * xb.y + w3 * xb.z + w4 * xb.w;
        }
        float scale = bg[c] * rsqrtf(bv[c] + 1e-5f);
        float shift = (cbias[c] - bm[c]) * scale + bb[c];
        float r[4] = {a0 * scale + shift, a1 * scale + shift, a2 * scale + shift, a3 * scale + shift};
        int tb = t0 + tg * 4;
#pragma unroll
        for (int q = 0; q < 4; ++q) {
            int t = tb + q;
            if (t < T_LEN) xs[(size_t)(t * BATCH + b) * 512 + c] = r[q];
        }
    }
}

// ---------------------------------------------------------------------------
// Tiled fp32 GEMM: C[M][N] = [A | A2][M][K] * Bt[K][N] (+bias[N])
// BM=BN=128, BK=8, 256 threads, 8x8 per thread.
// ---------------------------------------------------------------------------
__global__ __launch_bounds__(256) void gemm_kernel(
    const float* __restrict__ A, const float* __restrict__ A2, int K1,
    const float* __restrict__ Bt, const float* __restrict__ bias,
    float* __restrict__ C, int N, int K)
{
    __shared__ float As[8][128];
    __shared__ float Bs[8][128];
    int m0 = blockIdx.x * 128;
    int n0 = blockIdx.y * 128;
    int tid = threadIdx.x;
    int ar = tid >> 1, akq = (tid & 1) * 4;
    int bk = tid >> 5, bn = (tid & 31) * 4;
    int ty = tid >> 4, tx = tid & 15;
    float acc[8][8];
#pragma unroll
    for (int i = 0; i < 8; i++)
#pragma unroll
        for (int j = 0; j < 8; j++) acc[i][j] = 0.f;

    for (int k0 = 0; k0 < K; k0 += 8) {
        int kg = k0 + akq;
        int r = m0 + ar;
        const float* src = (kg < K1) ? (A + (size_t)r * K1 + kg)
                                     : (A2 + (size_t)r * (K - K1) + (kg - K1));
        float4 av = *(const float4*)src;
        As[akq + 0][ar] = av.x; As[akq + 1][ar] = av.y;
        As[akq + 2][ar] = av.z; As[akq + 3][ar] = av.w;
        float4 bvv = *(const float4*)(Bt + (size_t)(k0 + bk) * N + n0 + bn);
        *(float4*)&Bs[bk][bn] = bvv;
        __syncthreads();
#pragma unroll
        for (int kk = 0; kk < 8; ++kk) {
            float4 a0 = *(const float4*)&As[kk][ty * 8];
            float4 a1 = *(const float4*)&As[kk][ty * 8 + 4];
            float4 b0 = *(const float4*)&Bs[kk][tx * 8];
            float4 b1 = *(const float4*)&Bs[kk][tx * 8 + 4];
            float ar_[8] = {a0.x, a0.y, a0.z, a0.w, a1.x, a1.y, a1.z, a1.w};
            float br_[8] = {b0.x, b0.y, b0.z, b0.w, b1.x, b1.y, b1.z, b1.w};
#pragma unroll
            for (int i = 0; i < 8; i++)
#pragma unroll
                for (int j = 0; j < 8; j++) acc[i][j] = fmaf(ar_[i], br_[j], acc[i][j]);
        }
        __syncthreads();
    }
#pragma unroll
    for (int i = 0; i < 8; i++) {
        size_t row = (size_t)(m0 + ty * 8 + i) * N + n0 + tx * 8;
#pragma unroll
        for (int j = 0; j < 8; j += 4) {
            float4 v;
            v.x = acc[i][j]; v.y = acc[i][j + 1]; v.z = acc[i][j + 2]; v.w = acc[i][j + 3];
            if (bias) {
                const float* bp = bias + n0 + tx * 8 + j;
                v.x += bp[0]; v.y += bp[1]; v.z += bp[2]; v.w += bp[3];
            }
            *(float4*)(C + row + j) = v;
        }
    }
}

// ---------------------------------------------------------------------------
// LSTM scan: one block per (batch, dir). 512 threads, 2 gate-columns each.
// pre [SROWS][2048] (dir-major gates, bias included), WPl [2][32][1024] uint4,
// out [SROWS][512] (fwd cols 0..255, bwd 256..511).
// Weights: g0..7 in LDS (128KB), g8..27 in VGPRs, g28..31 streamed from L2.
// ---------------------------------------------------------------------------
#define SCAN_LDS (131072 + 4096 + 512)
__global__ __launch_bounds__(512) void lstm_scan(
    const float* __restrict__ pre, const uint4* __restrict__ WPl,
    float* __restrict__ out)
{
    const int b = blockIdx.x >> 1;
    const int dir = blockIdx.x & 1;
    const int tid = threadIdx.x;
    const int j0 = tid, j1 = tid + 512;

    extern __shared__ char smem[];
    uint4* w_lds = (uint4*)smem;                  // [8*1024]
    float* gates = (float*)(smem + 131072);       // [1024]
    u32* h16 = (u32*)(smem + 131072 + 4096);      // [128]

    const uint4* wp = WPl + (size_t)dir * 32768;

    for (int i = tid; i < 8192; i += 512) w_lds[i] = wp[i];

    uint4 wr0[20], wr1[20];
#pragma unroll
    for (int i = 0; i < 20; ++i) {
        wr0[i] = wp[(8 + i) * 1024 + j0];
        wr1[i] = wp[(8 + i) * 1024 + j1];
    }
    if (tid < 128) h16[tid] = 0u;
    float c = 0.0f;
    __syncthreads();

    for (int step = 0; step < T_LEN; ++step) {
        int tt = dir ? (T_LEN - 1 - step) : step;
        // FIX (R1): dir-offset into the 2048-wide pre-activation row.
        // preB row = [dir0 gates 0..1023 | dir1 gates 1024..2047]; backward
        // blocks must read the second half. Without this the bwd LSTM consumed
        // the fwd input projections (absmax 6.67).
        const float* prow = pre + (size_t)(tt * BATCH + b) * 2048 + (dir << 10);
        float acc0 = prow[j0];
        float acc1 = prow[j1];
        uint4 ws0[4], ws1[4];
#pragma unroll
        for (int i = 0; i < 4; ++i) {
            ws0[i] = wp[(28 + i) * 1024 + j0];
            ws1[i] = wp[(28 + i) * 1024 + j1];
        }
#pragma unroll
        for (int g = 0; g < 8; ++g) {
            uint4 hv = *(const uint4*)&h16[g * 4];
            uint4 w0 = w_lds[g * 1024 + j0];
            uint4 w1 = w_lds[g * 1024 + j1];
            acc0 = dot2f(hv.x, w0.x, acc0); acc0 = dot2f(hv.y, w0.y, acc0);
            acc0 = dot2f(hv.z, w0.z, acc0); acc0 = dot2f(hv.w, w0.w, acc0);
            acc1 = dot2f(hv.x, w1.x, acc1); acc1 = dot2f(hv.y, w1.y, acc1);
            acc1 = dot2f(hv.z, w1.z, acc1); acc1 = dot2f(hv.w, w1.w, acc1);
        }
#pragma unroll
        for (int i = 0; i < 20; ++i) {
            uint4 hv = *(const uint4*)&h16[(8 + i) * 4];
            acc0 = dot2f(hv.x, wr0[i].x, acc0); acc0 = dot2f(hv.y, wr0[i].y, acc0);
            acc0 = dot2f(hv.z, wr0[i].z, acc0); acc0 = dot2f(hv.w, wr0[i].w, acc0);
            acc1 = dot2f(hv.x, wr1[i].x, acc1); acc1 = dot2f(hv.y, wr1[i].y, acc1);
            acc1 = dot2f(hv.z, wr1[i].z, acc1); acc1 = dot2f(hv.w, wr1[i].w, acc1);
        }
#pragma unroll
        for (int i = 0; i < 4; ++i) {
            uint4 hv = *(const uint4*)&h16[(28 + i) * 4];
            acc0 = dot2f(hv.x, ws0[i].x, acc0); acc0 = dot2f(hv.y, ws0[i].y, acc0);
            acc0 = dot2f(hv.z, ws0[i].z, acc0); acc0 = dot2f(hv.w, ws0[i].w, acc0);
            acc1 = dot2f(hv.x, ws1[i].x, acc1); acc1 = dot2f(hv.y, ws1[i].y, acc1);
            acc1 = dot2f(hv.z, ws1[i].z, acc1); acc1 = dot2f(hv.w, ws1[i].w, acc1);
        }
        gates[j0] = acc0;
        gates[j1] = acc1;
        __syncthreads();
        if (tid < 256) {
            float gi = gates[tid], gf = gates[tid + 256];
            float gg = gates[tid + 512], go = gates[tid + 768];
            c = fsigm(gf) * c + fsigm(gi) * ftanh_(gg);
            float h = fsigm(go) * ftanh_(c);
            out[(size_t)(tt * BATCH + b) * 512 + dir * 256 + tid] = h;
            float hn = __shfl_xor(h, 1);
            if ((tid & 1) == 0) h16[tid >> 1] = pack2h(h, hn);
        }
        __syncthreads();
    }
}

// ---------------------------------------------------------------------------
// LayerNorm over last dim 512. 256 threads = 4 rows (1 wave each).
// ---------------------------------------------------------------------------
__global__ __launch_bounds__(256) void ln_kernel(
    const float* __restrict__ in, const float* __restrict__ g,
    const float* __restrict__ b, float* __restrict__ out, int rows)
{
    int row = blockIdx.x * 4 + (threadIdx.x >> 6);
    if (row >= rows) return;
    int lane = threadIdx.x & 63;
    const float4* x = (const float4*)(in + (size_t)row * 512);
    float4 v0 = x[lane * 2], v1 = x[lane * 2 + 1];
    float s = v0.x + v0.y + v0.z + v0.w + v1.x + v1.y + v1.z + v1.w;
    float sq = v0.x * v0.x + v0.y * v0.y + v0.z * v0.z + v0.w * v0.w
             + v1.x * v1.x + v1.y * v1.y + v1.z * v1.z + v1.w * v1.w;
#pragma unroll
    for (int m = 1; m < 64; m <<= 1) {
        s += __shfl_xor(s, m);
        sq += __shfl_xor(sq, m);
    }
    float mu = s * (1.0f / 512.0f);
    float var = sq * (1.0f / 512.0f) - mu * mu;
    float rs = rsqrtf(var + 1e-5f);
    const float4* g4 = (const float4*)g;
    const float4* b4 = (const float4*)b;
    float4* o4 = (float4*)(out + (size_t)row * 512);
#pragma unroll
    for (int q = 0; q < 2; ++q) {
        float4 v = (q == 0) ? v0 : v1;
        float4 gg = g4[lane * 2 + q], bb = b4[lane * 2 + q];
        float4 r;
        r.x = (v.x - mu) * rs * gg.x + bb.x;
        r.y = (v.y - mu) * rs * gg.y + bb.y;
        r.z = (v.z - mu) * rs * gg.z + bb.z;
        r.w = (v.w - mu) * rs * gg.w + bb.w;
        o4[lane * 2 + q] = r;
    }
}

// ---------------------------------------------------------------------------
// CTC head: log_softmax(relu(cx) @ ctcWt) * mask. One block (128 thr) per row.
// ---------------------------------------------------------------------------
__global__ __launch_bounds__(128) void ctc_head_kernel(
    const float* __restrict__ cx, const float* __restrict__ ctcWt,
    const int* __restrict__ lens, float* __restrict__ out)
{
    int r = blockIdx.x;
    int t = r / BATCH, b = r - t * BATCH;
    int tid = threadIdx.x;
    __shared__ float xr[512];
    __shared__ float red[128];
    for (int i = tid; i < 512; i += 128) xr[i] = fmaxf(cx[(size_t)r * 512 + i], 0.0f);
    __syncthreads();
    float logit = 0.0f;
    if (tid < 80) {
#pragma unroll 8
        for (int k = 0; k < 512; ++k) logit += xr[k] * ctcWt[k * 80 + tid];
    }
    red[tid] = (tid < 80) ? logit : -1e30f;
    __syncthreads();
    for (int off = 64; off > 0; off >>= 1) {
        if (tid < off) red[tid] = fmaxf(red[tid], red[tid + off]);
        __syncthreads();
    }
    float m = red[0];
    __syncthreads();
    red[tid] = (tid < 80) ? __expf(logit - m) : 0.0f;
    __syncthreads();
    for (int off = 64; off > 0; off >>= 1) {
        if (tid < off) red[tid] += red[tid + off];
        __syncthreads();
    }
    float lsum = __logf(red[0]);
    if (tid < 80) {
        float lp = logit - m - lsum;
        out[(size_t)r * 80 + tid] = (t < lens[b]) ? lp : 0.0f;
    }
}

// ---------------------------------------------------------------------------
// Mel head: (mx @ melWt) * 6 - 6. One block (128 thr) per row.
// ---------------------------------------------------------------------------
__global__ __launch_bounds__(128) void mel_head_kernel(
    const float* __restrict__ mx, const float* __restrict__ melWt,
    float* __restrict__ out)
{
    int r = blockIdx.x;
    int tid = threadIdx.x;
    __shared__ float xr[512];
    for (int i = tid; i < 512; i += 128) xr[i] = mx[(size_t)r * 512 + i];
    __syncthreads();
    if (tid < 80) {
        float acc = 0.0f;
#pragma unroll 8
        for (int k = 0; k < 512; ++k) acc += xr[k] * melWt[k * 80 + tid];
        out[(size_t)r * 80 + tid] = acc * 6.0f - 6.0f;
    }
}

// ===========================================================================
extern "C" void kernel_launch(void* const* d_in, const int* in_sizes, int n_in,
                              void* d_out, int out_size, void* d_ws, size_t ws_size,
                              hipStream_t stream) {
    const float* mels = (const float*)d_in[0];
    const float* c1w = (const float*)d_in[1];
    const float* c1b = (const float*)d_in[2];
    const float* bn1g = (const float*)d_in[3];
    const float* bn1b = (const float*)d_in[4];
    const float* bn1m = (const float*)d_in[5];
    const float* bn1v = (const float*)d_in[6];
    const float* c2w = (const float*)d_in[7];
    const float* c2b = (const float*)d_in[8];
    const float* bn2g = (const float*)d_in[9];
    const float* bn2b = (const float*)d_in[10];
    const float* bn2m = (const float*)d_in[11];
    const float* bn2v = (const float*)d_in[12];
    const float* eWih = (const float*)d_in[13];
    const float* eWhh = (const float*)d_in[14];
    const float* eb   = (const float*)d_in[15];
    const float* elng = (const float*)d_in[16];
    const float* elnb = (const float*)d_in[17];
    const float* cWih = (const float*)d_in[18];
    const float* cWhh = (const float*)d_in[19];
    const float* cb   = (const float*)d_in[20];
    const float* ctcW = (const float*)d_in[21];
    const float* btlW = (const float*)d_in[22];
    const float* lng  = (const float*)d_in[23];
    const float* lnb  = (const float*)d_in[24];
    const float* dWih = (const float*)d_in[25];
    const float* dWhh = (const float*)d_in[26];
    const float* db   = (const float*)d_in[27];
    const float* melW = (const float*)d_in[28];
    const int* mel_lengths = (const int*)d_in[29];

    float* out = (float*)d_out;          // [SROWS*80 mel][SROWS*80 logprob]
    float* ws = (float*)d_ws;

    const size_t SLOTF = (size_t)SROWS * 512;   // 8,192,000
    float* slotA = ws;
    float* slotB = ws + SLOTF;
    float* hBuf  = ws + 2 * SLOTF;
    float* preB  = ws + 3 * SLOTF;                       // SROWS*2048
    float* wihT  = ws + 3 * SLOTF + (size_t)SROWS * 2048;
    float* btlT  = wihT + 6ull * 1048576;
    u32*  wpAll  = (u32*)(btlT + 524288);                // 6 * 262144 u32
    float* ctcT  = (float*)(wpAll + 6ull * 262144);
    float* melT  = ctcT + 40960;

    (void)hipFuncSetAttribute((const void*)lstm_scan,
                              hipFuncAttributeMaxDynamicSharedMemorySize, SCAN_LDS);
    (void)hipFuncSetAttribute((const void*)conv2_kernel,
                              hipFuncAttributeMaxDynamicSharedMemorySize, 512 * 72 * 4);

    // ---- weight prep ----
    for (int l = 0; l < 2; ++l) {
        transpose_kernel<<<2048, 256, 0, stream>>>(eWih + (size_t)l * 1048576,
                                                   wihT + (size_t)(0 + l) * 1048576, 2048, 512);
        transpose_kernel<<<2048, 256, 0, stream>>>(cWih + (size_t)l * 1048576,
                                                   wihT + (size_t)(2 + l) * 1048576, 2048, 512);
        transpose_kernel<<<2048, 256, 0, stream>>>(dWih + (size_t)l * 1048576,
                                                   wihT + (size_t)(4 + l) * 1048576, 2048, 512);
    }
    transpose_kernel<<<2048, 256, 0, stream>>>(btlW, btlT, 512, 1024);
    transpose_kernel<<<160, 256, 0, stream>>>(ctcW, ctcT, 80, 512);
    transpose_kernel<<<160, 256, 0, stream>>>(melW, melT, 80, 512);
    prep_whh_kernel<<<2048, 256, 0, stream>>>(eWhh, wpAll + 0ull * 262144, 2 * 262144);
    prep_whh_kernel<<<2048, 256, 0, stream>>>(cWhh, wpAll + 2ull * 262144, 2 * 262144);
    prep_whh_kernel<<<2048, 256, 0, stream>>>(dWhh, wpAll + 4ull * 262144, 2 * 262144);

    // ---- prenet ----
    conv1_kernel<<<dim3(16, 16), 256, 0, stream>>>(mels, c1w, c1b, bn1g, bn1b, bn1m, bn1v, hBuf);
    conv2_kernel<<<dim3(16, 16), 256, 512 * 72 * 4, stream>>>(hBuf, c2w, c2b, bn2g, bn2b, bn2m, bn2v, slotB);

    dim3 g2048(125, 16), g512(125, 4);
    // ---- encoder ----
    gemm_kernel<<<g2048, 256, 0, stream>>>(slotB, nullptr, 512, wihT + 0ull * 1048576, eb, preB, 2048, 512);
    lstm_scan<<<32, 512, SCAN_LDS, stream>>>(preB, (const uint4*)(wpAll + 0ull * 262144), slotA);
    gemm_kernel<<<g2048, 256, 0, stream>>>(slotA, nullptr, 512, wihT + 1ull * 1048576, eb + 2048, preB, 2048, 512);
    lstm_scan<<<32, 512, SCAN_LDS, stream>>>(preB, (const uint4*)(wpAll + 1ull * 262144), slotB);
    ln_kernel<<<4000, 256, 0, stream>>>(slotB, elng, elnb, hBuf, SROWS);
    // ---- ctc decoder ----
    gemm_kernel<<<g2048, 256, 0, stream>>>(hBuf, nullptr, 512, wihT + 2ull * 1048576, cb, preB, 2048, 512);
    lstm_scan<<<32, 512, SCAN_LDS, stream>>>(preB, (const uint4*)(wpAll + 2ull * 262144), slotA);
    gemm_kernel<<<g2048, 256, 0, stream>>>(slotA, nullptr, 512, wihT + 3ull * 1048576, cb + 2048, preB, 2048, 512);
    lstm_scan<<<32, 512, SCAN_LDS, stream>>>(preB, (const uint4*)(wpAll + 3ull * 262144), slotB); // cx
    ctc_head_kernel<<<SROWS, 128, 0, stream>>>(slotB, ctcT, mel_lengths, out + (size_t)SROWS * 80);
    // ---- bottleneck: cat(h, cx) @ btlW.T -> LN ----
    gemm_kernel<<<g512, 256, 0, stream>>>(hBuf, slotB, 512, btlT, nullptr, preB, 512, 1024);
    ln_kernel<<<4000, 256, 0, stream>>>(preB, lng, lnb, slotA, SROWS);
    // ---- mel decoder ----
    gemm_kernel<<<g2048, 256, 0, stream>>>(slotA, nullptr, 512, wihT + 4ull * 1048576, db, preB, 2048, 512);
    lstm_scan<<<32, 512, SCAN_LDS, stream>>>(preB, (const uint4*)(wpAll + 4ull * 262144), hBuf);
    gemm_kernel<<<g2048, 256, 0, stream>>>(hBuf, nullptr, 512, wihT + 5ull * 1048576, db + 2048, preB, 2048, 512);
    lstm_scan<<<32, 512, SCAN_LDS, stream>>>(preB, (const uint4*)(wpAll + 5ull * 262144), slotB); // mx
    mel_head_kernel<<<SROWS, 128, 0, stream>>>(slotB, melT, out);
}

// Round 3
// 12484.103 us; speedup vs baseline: 1.4687x; 1.4687x over previous
//
#include <hip/hip_runtime.h>
#include <hip/hip_fp16.h>

// ============================================================================
// ATTNAligner forward. R3: MFMA fp16 GEMMs (pipeline + conv2-as-GEMM),
// lstm_scan register-spill fix via __launch_bounds__(512,2) + 9/21/2 split.
// ============================================================================

typedef unsigned int u32;
typedef _Float16 h2_t __attribute__((ext_vector_type(2)));
typedef _Float16 f16x8 __attribute__((ext_vector_type(8)));
typedef float f32x4 __attribute__((ext_vector_type(4)));
union U32H2 { u32 u; h2_t h; };

#define T_LEN 1000
#define BATCH 16
#define SROWS (T_LEN * BATCH)

__device__ __forceinline__ float dot2f(u32 a, u32 b, float c) {
#if __has_builtin(__builtin_amdgcn_fdot2)
    U32H2 ua; ua.u = a; U32H2 ub; ub.u = b;
    return __builtin_amdgcn_fdot2(ua.h, ub.h, c, false);
#else
    U32H2 ua; ua.u = a; U32H2 ub; ub.u = b;
    return c + (float)ua.h.x * (float)ub.h.x + (float)ua.h.y * (float)ub.h.y;
#endif
}

__device__ __forceinline__ u32 pack2h(float a, float b) {
    h2_t p; p.x = (_Float16)a; p.y = (_Float16)b;
    U32H2 u; u.h = p; return u.u;
}

__device__ __forceinline__ float fsigm(float x) { return 1.0f / (1.0f + __expf(-x)); }
__device__ __forceinline__ float ftanh_(float x) {
    x = fminf(fmaxf(x, -15.0f), 15.0f);
    float e = __expf(-2.0f * x);
    return (1.0f - e) / (1.0f + e);
}

// ---------------------------------------------------------------------------
// Generic transpose: src[R][C] -> dst[C][R]  (fp32; ctc/mel head weights)
// ---------------------------------------------------------------------------
__global__ void transpose_kernel(const float* __restrict__ src, float* __restrict__ dst,
                                 int R, int C) {
    int total = R * C;
    for (int i = blockIdx.x * blockDim.x + threadIdx.x; i < total; i += gridDim.x * blockDim.x) {
        int r = i / C, c = i - r * C;
        dst[(size_t)c * R + r] = src[i];
    }
}

// ---------------------------------------------------------------------------
// Pack recurrent weights Whh [layers][2][1024][256] f32
//   -> wp [layers][2][32 g][1024 j][4 q] u32, u32 = half2(W[j][8g+2q], W[j][8g+2q+1])
// ---------------------------------------------------------------------------
__global__ void prep_whh_kernel(const float* __restrict__ whh, u32* __restrict__ wp, int total) {
    for (int idx = blockIdx.x * blockDim.x + threadIdx.x; idx < total; idx += gridDim.x * blockDim.x) {
        int q = idx & 3;
        int j = (idx >> 2) & 1023;
        int g = (idx >> 12) & 31;
        int d = (idx >> 17) & 1;
        int l = idx >> 18;
        int k = g * 8 + q * 2;
        const float* s = whh + ((size_t)(l * 2 + d) * 1024 + j) * 256 + k;
        wp[idx] = pack2h(s[0], s[1]);
    }
}

// ---------------------------------------------------------------------------
// Pack a weight matrix into MFMA-16x16x32 B-fragment order (fp16).
// Logical B[k][n] = src[n*sn + k*sk + off] (fp32).
// dst layout: [nt = n/16][ks = k/32][lane 64][i 8],
//   n = nt*16 + (lane&15), k = ks*32 + (lane>>4)*8 + i.
// ---------------------------------------------------------------------------
__global__ void pack_b_kernel(const float* __restrict__ src, _Float16* __restrict__ dst,
                              int N, int K, int sn, int sk, int off) {
    int total = N * K;
    int kst = K >> 5;
    for (int idx = blockIdx.x * blockDim.x + threadIdx.x; idx < total; idx += gridDim.x * blockDim.x) {
        int i = idx & 7;
        int lane = (idx >> 3) & 63;
        int rest = idx >> 9;
        int ks = rest % kst;
        int nt = rest / kst;
        int n = nt * 16 + (lane & 15);
        int k = ks * 32 + (lane >> 4) * 8 + i;
        dst[idx] = (_Float16)src[(size_t)n * sn + (size_t)k * sk + off];
    }
}

// ---------------------------------------------------------------------------
// Conv1: mels [B][80][T] (normalized inline) -> y1 [B][512][T] fp32, K=5 + BN
// ---------------------------------------------------------------------------
__global__ __launch_bounds__(256) void conv1_kernel(
    const float* __restrict__ mels, const float* __restrict__ w,
    const float* __restrict__ cbias, const float* __restrict__ bg,
    const float* __restrict__ bb, const float* __restrict__ bm,
    const float* __restrict__ bv, float* __restrict__ y1)
{
    __shared__ float xin[80 * 72];
    int t0 = blockIdx.x * 64;
    int b = blockIdx.y;
    int tid = threadIdx.x;
    for (int idx = tid; idx < 80 * 68; idx += 256) {
        int m = idx / 68, i = idx - m * 68;
        int t = t0 - 4 + i;
        float v = 0.0f;
        if (t >= 0 && t < T_LEN) v = mels[(size_t)(b * 80 + m) * T_LEN + t] * (1.0f / 6.0f) + 1.0f;
        xin[m * 72 + i] = v;
    }
    __syncthreads();
    int tg = tid & 15, cl = tid >> 4;
    for (int pass = 0; pass < 32; ++pass) {
        int c = pass * 16 + cl;
        const float* wc = w + (size_t)c * 400;
        float a0 = 0, a1 = 0, a2 = 0, a3 = 0;
        for (int m = 0; m < 80; ++m) {
            float4 xa = *(const float4*)&xin[m * 72 + tg * 4];
            float4 xb = *(const float4*)&xin[m * 72 + tg * 4 + 4];
            float w0 = wc[m * 5 + 0], w1 = wc[m * 5 + 1], w2 = wc[m * 5 + 2];
            float w3 = wc[m * 5 + 3], w4 = wc[m * 5 + 4];
            a0 += w0 * xa.x + w1 * xa.y + w2 * xa.z + w3 * xa.w + w4 * xb.x;
            a1 += w0 * xa.y + w1 * xa.z + w2 * xa.w + w3 * xb.x + w4 * xb.y;
            a2 += w0 * xa.z + w1 * xa.w + w2 * xb.x + w3 * xb.y + w4 * xb.z;
            a3 += w0 * xa.w + w1 * xb.x + w2 * xb.y + w3 * xb.z + w4 * xb.w;
        }
        float scale = bg[c] * rsqrtf(bv[c] + 1e-5f);
        float shift = (cbias[c] - bm[c]) * scale + bb[c];
        int tb = t0 + tg * 4;
        float* yp = y1 + (size_t)(b * 512 + c) * T_LEN + tb;
        if (tb + 0 < T_LEN) yp[0] = a0 * scale + shift;
        if (tb + 1 < T_LEN) yp[1] = a1 * scale + shift;
        if (tb + 2 < T_LEN) yp[2] = a2 * scale + shift;
        if (tb + 3 < T_LEN) yp[3] = a3 * scale + shift;
    }
}

// ---------------------------------------------------------------------------
// Relayout conv1 output: y1 [B][512][T] fp32 -> f0 [(t*16+b)][512] fp16
// grid (16 t-tiles, 8 c-tiles, 16 b), 256 threads
// ---------------------------------------------------------------------------
__global__ __launch_bounds__(256) void relayout_kernel(
    const float* __restrict__ y1, _Float16* __restrict__ dst)
{
    __shared__ float tile[64][65];
    int t0 = blockIdx.x * 64;
    int c0 = blockIdx.y * 64;
    int b = blockIdx.z;
    int tid = threadIdx.x;
#pragma unroll
    for (int q = 0; q < 16; ++q) {
        int lin = tid + q * 256;
        int cl = lin >> 6, tl = lin & 63;
        int t = t0 + tl;
        tile[cl][tl] = (t < T_LEN) ? y1[(size_t)(b * 512 + c0 + cl) * T_LEN + t] : 0.0f;
    }
    __syncthreads();
#pragma unroll
    for (int q = 0; q < 16; ++q) {
        int lin = tid + q * 256;
        int rl = lin >> 6, cc = lin & 63;
        int t = t0 + rl;
        if (t < T_LEN)
            dst[(size_t)(t * BATCH + b) * 512 + c0 + cc] = (_Float16)tile[cc][rl];
    }
}

// ---------------------------------------------------------------------------
// MFMA fp16 GEMM. C[M=16000][N] = A[M][K] @ Bpack (+ bias / BN epilogue).
// MODE 0: A fp16 [M][K1] (+A2 [M][K-K1] concat), C fp32 (+bias).
// MODE 1: conv2 — A = f0 [M][512] with 5 k-phases, row shift (kph-4)*16;
//         C fp16 with BatchNorm folded.
// 128x128 tile, 8 waves (2x4), per wave 64x32 = 4x2 MFMA tiles, BK=32.
// ---------------------------------------------------------------------------
template<int MODE>
__global__ __launch_bounds__(512, 2) void gemm_mfma(
    const _Float16* __restrict__ A, const _Float16* __restrict__ A2, int K1,
    const uint4* __restrict__ Bp, const float* __restrict__ bias,
    float* __restrict__ C32, _Float16* __restrict__ C16,
    const float* __restrict__ cvb, const float* __restrict__ bg,
    const float* __restrict__ bb, const float* __restrict__ bm,
    const float* __restrict__ bv, int N, int K)
{
    __shared__ _Float16 At[128 * 40];   // 128 rows x 32 f16, stride 40 (pad 8)
    const int m0 = blockIdx.x * 128, n0 = blockIdx.y * 128;
    const int tid = threadIdx.x, lane = tid & 63, w = tid >> 6;
    const int wm = w >> 2, wn = w & 3;
    const int srow = tid >> 2, sseg = tid & 3;
    const int ksteps = K >> 5;
    f32x4 acc[4][2];
#pragma unroll
    for (int i = 0; i < 4; ++i) { acc[i][0] = (f32x4)0.0f; acc[i][1] = (f32x4)0.0f; }

    for (int ks = 0; ks < ksteps; ++ks) {
        int k0 = ks << 5;
        uint4 av;
        if (MODE == 1) {
            int kph = k0 >> 9, kk = k0 & 511;
            int rsrc = m0 + srow + (kph - 4) * 16;
            if (rsrc >= 0) av = *(const uint4*)(A + (size_t)rsrc * 512 + kk + sseg * 8);
            else { av.x = av.y = av.z = av.w = 0u; }
        } else {
            int col = k0 + sseg * 8;
            const _Float16* src = (col < K1) ? (A + (size_t)(m0 + srow) * K1 + col)
                                             : (A2 + (size_t)(m0 + srow) * (K - K1) + (col - K1));
            av = *(const uint4*)src;
        }
        __syncthreads();
        *(uint4*)&At[srow * 40 + sseg * 8] = av;
        __syncthreads();

        f16x8 bf[2];
#pragma unroll
        for (int ct = 0; ct < 2; ++ct) {
            int nt = (n0 >> 4) + wn * 2 + ct;
            int bblk = (MODE == 1) ? ((ks >> 4) * 512 + nt * 16 + (ks & 15))
                                   : (nt * ksteps + ks);
            uint4 braw = Bp[(size_t)bblk * 64 + lane];
            bf[ct] = *(f16x8*)&braw;
        }
#pragma unroll
        for (int rt = 0; rt < 4; ++rt) {
            f16x8 af = *(f16x8*)&At[(wm * 64 + rt * 16 + (lane & 15)) * 40 + (lane >> 4) * 8];
            acc[rt][0] = __builtin_amdgcn_mfma_f32_16x16x32_f16(af, bf[0], acc[rt][0], 0, 0, 0);
            acc[rt][1] = __builtin_amdgcn_mfma_f32_16x16x32_f16(af, bf[1], acc[rt][1], 0, 0, 0);
        }
    }

    // epilogue: C row = m0 + wm*64 + rt*16 + (lane>>4)*4 + rr, col = n0 + wn*32 + ct*16 + (lane&15)
    const int r0 = m0 + wm * 64 + (lane >> 4) * 4;
    const int cb0 = n0 + wn * 32 + (lane & 15);
#pragma unroll
    for (int ct = 0; ct < 2; ++ct) {
        int col = cb0 + ct * 16;
        float badd = 0.0f, sc = 0.0f, sh = 0.0f;
        if (MODE == 0) { if (bias) badd = bias[col]; }
        else {
            sc = bg[col] * rsqrtf(bv[col] + 1e-5f);
            sh = (cvb[col] - bm[col]) * sc + bb[col];
        }
#pragma unroll
        for (int rt = 0; rt < 4; ++rt) {
#pragma unroll
            for (int rr = 0; rr < 4; ++rr) {
                int row = r0 + rt * 16 + rr;
                float v = acc[rt][ct][rr];
                if (MODE == 0) C32[(size_t)row * N + col] = v + badd;
                else           C16[(size_t)row * 512 + col] = (_Float16)(v * sc + sh);
            }
        }
    }
}

// ---------------------------------------------------------------------------
// LSTM scan: one block per (batch, dir). 512 threads, 2 gate-columns each.
// Weights (uint4 groups g0..31 over k): g0..8 LDS (144KB), g9..29 regs
// (42 uint4 = 168 VGPR), g30..31 streamed from L2 (32KB/step).
// __launch_bounds__(512,2) -> 256-VGPR cap: R2's 116-VGPR spill fix.
// ---------------------------------------------------------------------------
#define SCAN_LDS (147456 + 4096 + 512)
__global__ __launch_bounds__(512, 2) void lstm_scan(
    const float* __restrict__ pre, const uint4* __restrict__ WPl,
    float* __restrict__ out32, _Float16* __restrict__ out16)
{
    const int b = blockIdx.x >> 1;
    const int dir = blockIdx.x & 1;
    const int tid = threadIdx.x;
    const int j0 = tid, j1 = tid + 512;

    extern __shared__ char smem[];
    uint4* w_lds = (uint4*)smem;                    // [9*1024]
    float* gates = (float*)(smem + 147456);         // [1024]
    u32* h16 = (u32*)(smem + 147456 + 4096);        // [128]

    const uint4* wp = WPl + (size_t)dir * 32768;

    for (int i = tid; i < 9216; i += 512) w_lds[i] = wp[i];

    uint4 wr0[21], wr1[21];
#pragma unroll
    for (int i = 0; i < 21; ++i) {
        wr0[i] = wp[(9 + i) * 1024 + j0];
        wr1[i] = wp[(9 + i) * 1024 + j1];
    }
    if (tid < 128) h16[tid] = 0u;
    float c = 0.0f;
    __syncthreads();

    for (int step = 0; step < T_LEN; ++step) {
        int tt = dir ? (T_LEN - 1 - step) : step;
        const float* prow = pre + (size_t)(tt * BATCH + b) * 2048 + (dir << 10);
        float acc0 = prow[j0];
        float acc1 = prow[j1];
        uint4 ws0[2], ws1[2];
#pragma unroll
        for (int i = 0; i < 2; ++i) {
            ws0[i] = wp[(30 + i) * 1024 + j0];
            ws1[i] = wp[(30 + i) * 1024 + j1];
        }
#pragma unroll
        for (int g = 0; g < 9; ++g) {
            uint4 hv = *(const uint4*)&h16[g * 4];
            uint4 w0 = w_lds[g * 1024 + j0];
            uint4 w1 = w_lds[g * 1024 + j1];
            acc0 = dot2f(hv.x, w0.x, acc0); acc0 = dot2f(hv.y, w0.y, acc0);
            acc0 = dot2f(hv.z, w0.z, acc0); acc0 = dot2f(hv.w, w0.w, acc0);
            acc1 = dot2f(hv.x, w1.x, acc1); acc1 = dot2f(hv.y, w1.y, acc1);
            acc1 = dot2f(hv.z, w1.z, acc1); acc1 = dot2f(hv.w, w1.w, acc1);
        }
#pragma unroll
        for (int i = 0; i < 21; ++i) {
            uint4 hv = *(const uint4*)&h16[(9 + i) * 4];
            acc0 = dot2f(hv.x, wr0[i].x, acc0); acc0 = dot2f(hv.y, wr0[i].y, acc0);
            acc0 = dot2f(hv.z, wr0[i].z, acc0); acc0 = dot2f(hv.w, wr0[i].w, acc0);
            acc1 = dot2f(hv.x, wr1[i].x, acc1); acc1 = dot2f(hv.y, wr1[i].y, acc1);
            acc1 = dot2f(hv.z, wr1[i].z, acc1); acc1 = dot2f(hv.w, wr1[i].w, acc1);
        }
#pragma unroll
        for (int i = 0; i < 2; ++i) {
            uint4 hv = *(const uint4*)&h16[(30 + i) * 4];
            acc0 = dot2f(hv.x, ws0[i].x, acc0); acc0 = dot2f(hv.y, ws0[i].y, acc0);
            acc0 = dot2f(hv.z, ws0[i].z, acc0); acc0 = dot2f(hv.w, ws0[i].w, acc0);
            acc1 = dot2f(hv.x, ws1[i].x, acc1); acc1 = dot2f(hv.y, ws1[i].y, acc1);
            acc1 = dot2f(hv.z, ws1[i].z, acc1); acc1 = dot2f(hv.w, ws1[i].w, acc1);
        }
        gates[j0] = acc0;
        gates[j1] = acc1;
        __syncthreads();
        if (tid < 256) {
            float gi = gates[tid], gf = gates[tid + 256];
            float gg = gates[tid + 512], go = gates[tid + 768];
            c = fsigm(gf) * c + fsigm(gi) * ftanh_(gg);
            float h = fsigm(go) * ftanh_(c);
            size_t orow = (size_t)(tt * BATCH + b) * 512 + dir * 256 + tid;
            if (out32) out32[orow] = h;
            if (out16) out16[orow] = (_Float16)h;
            float hn = __shfl_xor(h, 1);
            if ((tid & 1) == 0) h16[tid >> 1] = pack2h(h, hn);
        }
        __syncthreads();
    }
}

// ---------------------------------------------------------------------------
// LayerNorm over last dim 512, fp32 in -> fp16 out. 256 thr = 4 rows.
// ---------------------------------------------------------------------------
__global__ __launch_bounds__(256) void ln_kernel(
    const float* __restrict__ in, const float* __restrict__ g,
    const float* __restrict__ b, _Float16* __restrict__ out, int rows)
{
    int row = blockIdx.x * 4 + (threadIdx.x >> 6);
    if (row >= rows) return;
    int lane = threadIdx.x & 63;
    const float4* x = (const float4*)(in + (size_t)row * 512);
    float4 v0 = x[lane * 2], v1 = x[lane * 2 + 1];
    float s = v0.x + v0.y + v0.z + v0.w + v1.x + v1.y + v1.z + v1.w;
    float sq = v0.x * v0.x + v0.y * v0.y + v0.z * v0.z + v0.w * v0.w
             + v1.x * v1.x + v1.y * v1.y + v1.z * v1.z + v1.w * v1.w;
#pragma unroll
    for (int m = 1; m < 64; m <<= 1) {
        s += __shfl_xor(s, m);
        sq += __shfl_xor(sq, m);
    }
    float mu = s * (1.0f / 512.0f);
    float var = sq * (1.0f / 512.0f) - mu * mu;
    float rs = rsqrtf(var + 1e-5f);
    const float4* g4 = (const float4*)g;
    const float4* b4 = (const float4*)b;
    f16x8 r;
    float vv[8] = {v0.x, v0.y, v0.z, v0.w, v1.x, v1.y, v1.z, v1.w};
    float4 gg0 = g4[lane * 2], gg1 = g4[lane * 2 + 1];
    float4 bb0 = b4[lane * 2], bb1 = b4[lane * 2 + 1];
    float gA[8] = {gg0.x, gg0.y, gg0.z, gg0.w, gg1.x, gg1.y, gg1.z, gg1.w};
    float bA[8] = {bb0.x, bb0.y, bb0.z, bb0.w, bb1.x, bb1.y, bb1.z, bb1.w};
#pragma unroll
    for (int q = 0; q < 8; ++q) r[q] = (_Float16)((vv[q] - mu) * rs * gA[q] + bA[q]);
    *(f16x8*)&out[(size_t)row * 512 + lane * 8] = r;
}

// ---------------------------------------------------------------------------
// CTC head: log_softmax(relu(cx) @ ctcWt) * mask. One block (128 thr) per row.
// ---------------------------------------------------------------------------
__global__ __launch_bounds__(128) void ctc_head_kernel(
    const float* __restrict__ cx, const float* __restrict__ ctcWt,
    const int* __restrict__ lens, float* __restrict__ out)
{
    int r = blockIdx.x;
    int t = r / BATCH, b = r - t * BATCH;
    int tid = threadIdx.x;
    __shared__ float xr[512];
    __shared__ float red[128];
    for (int i = tid; i < 512; i += 128) xr[i] = fmaxf(cx[(size_t)r * 512 + i], 0.0f);
    __syncthreads();
    float logit = 0.0f;
    if (tid < 80) {
#pragma unroll 8
        for (int k = 0; k < 512; ++k) logit += xr[k] * ctcWt[k * 80 + tid];
    }
    red[tid] = (tid < 80) ? logit : -1e30f;
    __syncthreads();
    for (int off = 64; off > 0; off >>= 1) {
        if (tid < off) red[tid] = fmaxf(red[tid], red[tid + off]);
        __syncthreads();
    }
    float m = red[0];
    __syncthreads();
    red[tid] = (tid < 80) ? __expf(logit - m) : 0.0f;
    __syncthreads();
    for (int off = 64; off > 0; off >>= 1) {
        if (tid < off) red[tid] += red[tid + off];
        __syncthreads();
    }
    float lsum = __logf(red[0]);
    if (tid < 80) {
        float lp = logit - m - lsum;
        out[(size_t)r * 80 + tid] = (t < lens[b]) ? lp : 0.0f;
    }
}

// ---------------------------------------------------------------------------
// Mel head: (mx @ melWt) * 6 - 6. One block (128 thr) per row.
// ---------------------------------------------------------------------------
__global__ __launch_bounds__(128) void mel_head_kernel(
    const float* __restrict__ mx, const float* __restrict__ melWt,
    float* __restrict__ out)
{
    int r = blockIdx.x;
    int tid = threadIdx.x;
    __shared__ float xr[512];
    for (int i = tid; i < 512; i += 128) xr[i] = mx[(size_t)r * 512 + i];
    __syncthreads();
    if (tid < 80) {
        float acc = 0.0f;
#pragma unroll 8
        for (int k = 0; k < 512; ++k) acc += xr[k] * melWt[k * 80 + tid];
        out[(size_t)r * 80 + tid] = acc * 6.0f - 6.0f;
    }
}

// ===========================================================================
extern "C" void kernel_launch(void* const* d_in, const int* in_sizes, int n_in,
                              void* d_out, int out_size, void* d_ws, size_t ws_size,
                              hipStream_t stream) {
    const float* mels = (const float*)d_in[0];
    const float* c1w = (const float*)d_in[1];
    const float* c1b = (const float*)d_in[2];
    const float* bn1g = (const float*)d_in[3];
    const float* bn1b = (const float*)d_in[4];
    const float* bn1m = (const float*)d_in[5];
    const float* bn1v = (const float*)d_in[6];
    const float* c2w = (const float*)d_in[7];
    const float* c2b = (const float*)d_in[8];
    const float* bn2g = (const float*)d_in[9];
    const float* bn2b = (const float*)d_in[10];
    const float* bn2m = (const float*)d_in[11];
    const float* bn2v = (const float*)d_in[12];
    const float* eWih = (const float*)d_in[13];
    const float* eWhh = (const float*)d_in[14];
    const float* eb   = (const float*)d_in[15];
    const float* elng = (const float*)d_in[16];
    const float* elnb = (const float*)d_in[17];
    const float* cWih = (const float*)d_in[18];
    const float* cWhh = (const float*)d_in[19];
    const float* cb   = (const float*)d_in[20];
    const float* ctcW = (const float*)d_in[21];
    const float* btlW = (const float*)d_in[22];
    const float* lng  = (const float*)d_in[23];
    const float* lnb  = (const float*)d_in[24];
    const float* dWih = (const float*)d_in[25];
    const float* dWhh = (const float*)d_in[26];
    const float* db   = (const float*)d_in[27];
    const float* melW = (const float*)d_in[28];
    const int* mel_lengths = (const int*)d_in[29];

    float* out = (float*)d_out;          // [SROWS*80 mel][SROWS*80 logprob]
    float* ws = (float*)d_ws;

    // ---- workspace layout ----
    float* preB = ws;                                   // 32,768,000 f32
    float* s32  = ws + 32768000;                        //  8,192,000 f32
    _Float16* f0 = (_Float16*)(ws + 40960000);          //  8,192,000 f16 each
    _Float16* f1 = f0 + 8192000;
    _Float16* f2 = f1 + 8192000;
    _Float16* f3 = f2 + 8192000;
    _Float16* BP    = f3 + 8192000;                     // 6 x 1,048,576 f16
    _Float16* BPbtl = BP + 6ull * 1048576;              // 524,288 f16
    _Float16* BPcv  = BPbtl + 524288;                   // 5 x 262,144 f16
    u32* wpAll = (u32*)(BPcv + 5ull * 262144);          // 6 x 262,144 u32
    float* ctcT = (float*)(wpAll + 6ull * 262144);      // 40,960 f32
    float* melT = ctcT + 40960;                         // 40,960 f32
    // total ~258.6 MB

    (void)hipFuncSetAttribute((const void*)lstm_scan,
                              hipFuncAttributeMaxDynamicSharedMemorySize, SCAN_LDS);

    // ---- weight prep ----
    transpose_kernel<<<160, 256, 0, stream>>>(ctcW, ctcT, 80, 512);
    transpose_kernel<<<160, 256, 0, stream>>>(melW, melT, 80, 512);
    prep_whh_kernel<<<2048, 256, 0, stream>>>(eWhh, wpAll + 0ull * 262144, 2 * 262144);
    prep_whh_kernel<<<2048, 256, 0, stream>>>(cWhh, wpAll + 2ull * 262144, 2 * 262144);
    prep_whh_kernel<<<2048, 256, 0, stream>>>(dWhh, wpAll + 4ull * 262144, 2 * 262144);
    // layer input-proj packs: B[k][n] = Wih[l](n, k): src[n*512 + k]
    for (int l = 0; l < 2; ++l) {
        pack_b_kernel<<<1024, 256, 0, stream>>>(eWih + (size_t)l * 1048576,
                                                BP + (size_t)(0 + l) * 1048576, 2048, 512, 512, 1, 0);
        pack_b_kernel<<<1024, 256, 0, stream>>>(cWih + (size_t)l * 1048576,
                                                BP + (size_t)(2 + l) * 1048576, 2048, 512, 512, 1, 0);
        pack_b_kernel<<<1024, 256, 0, stream>>>(dWih + (size_t)l * 1048576,
                                                BP + (size_t)(4 + l) * 1048576, 2048, 512, 512, 1, 0);
    }
    // bottleneck: B[k][n] = btlW[n][k]: src[n*1024 + k], N=512, K=1024
    pack_b_kernel<<<1024, 256, 0, stream>>>(btlW, BPbtl, 512, 1024, 1024, 1, 0);
    // conv2 phases: B_kph[m][c] = c2w[c][m][kph]: src[n*2560 + k*5 + kph]
    for (int kph = 0; kph < 5; ++kph)
        pack_b_kernel<<<512, 256, 0, stream>>>(c2w, BPcv + (size_t)kph * 262144,
                                               512, 512, 2560, 5, kph);

    // ---- prenet ----
    conv1_kernel<<<dim3(16, 16), 256, 0, stream>>>(mels, c1w, c1b, bn1g, bn1b, bn1m, bn1v, s32);
    relayout_kernel<<<dim3(16, 8, 16), 256, 0, stream>>>(s32, f0);
    gemm_mfma<1><<<dim3(125, 4), 512, 0, stream>>>(f0, nullptr, 0, (const uint4*)BPcv, nullptr,
                                                   nullptr, f1, c2b, bn2g, bn2b, bn2m, bn2v, 512, 2560);

    dim3 gN2048(125, 16), gN512(125, 4);
    const uint4* BPu = (const uint4*)BP;
    // ---- encoder ----
    gemm_mfma<0><<<gN2048, 512, 0, stream>>>(f1, nullptr, 512, BPu + 0ull * 131072, eb,
                                             preB, nullptr, nullptr, nullptr, nullptr, nullptr, nullptr, 2048, 512);
    lstm_scan<<<32, 512, SCAN_LDS, stream>>>(preB, (const uint4*)(wpAll + 0ull * 262144), nullptr, f2);
    gemm_mfma<0><<<gN2048, 512, 0, stream>>>(f2, nullptr, 512, BPu + 1ull * 131072, eb + 2048,
                                             preB, nullptr, nullptr, nullptr, nullptr, nullptr, nullptr, 2048, 512);
    lstm_scan<<<32, 512, SCAN_LDS, stream>>>(preB, (const uint4*)(wpAll + 1ull * 262144), s32, nullptr);
    ln_kernel<<<4000, 256, 0, stream>>>(s32, elng, elnb, f2, SROWS);   // f2 = h (fp16)
    // ---- ctc decoder ----
    gemm_mfma<0><<<gN2048, 512, 0, stream>>>(f2, nullptr, 512, BPu + 2ull * 131072, cb,
                                             preB, nullptr, nullptr, nullptr, nullptr, nullptr, nullptr, 2048, 512);
    lstm_scan<<<32, 512, SCAN_LDS, stream>>>(preB, (const uint4*)(wpAll + 2ull * 262144), nullptr, f3);
    gemm_mfma<0><<<gN2048, 512, 0, stream>>>(f3, nullptr, 512, BPu + 3ull * 131072, cb + 2048,
                                             preB, nullptr, nullptr, nullptr, nullptr, nullptr, nullptr, 2048, 512);
    lstm_scan<<<32, 512, SCAN_LDS, stream>>>(preB, (const uint4*)(wpAll + 3ull * 262144), s32, f1); // cx
    ctc_head_kernel<<<SROWS, 128, 0, stream>>>(s32, ctcT, mel_lengths, out + (size_t)SROWS * 80);
    // ---- bottleneck: [h | cx] @ btlW.T -> LN ----
    gemm_mfma<0><<<gN512, 512, 0, stream>>>(f2, f1, 512, (const uint4*)BPbtl, nullptr,
                                            preB, nullptr, nullptr, nullptr, nullptr, nullptr, nullptr, 512, 1024);
    ln_kernel<<<4000, 256, 0, stream>>>(preB, lng, lnb, f3, SROWS);    // f3 = bottleneck (fp16)
    // ---- mel decoder ----
    gemm_mfma<0><<<gN2048, 512, 0, stream>>>(f3, nullptr, 512, BPu + 4ull * 131072, db,
                                             preB, nullptr, nullptr, nullptr, nullptr, nullptr, nullptr, 2048, 512);
    lstm_scan<<<32, 512, SCAN_LDS, stream>>>(preB, (const uint4*)(wpAll + 4ull * 262144), nullptr, f2);
    gemm_mfma<0><<<gN2048, 512, 0, stream>>>(f2, nullptr, 512, BPu + 5ull * 131072, db + 2048,
                                             preB, nullptr, nullptr, nullptr, nullptr, nullptr, nullptr, 2048, 512);
    lstm_scan<<<32, 512, SCAN_LDS, stream>>>(preB, (const uint4*)(wpAll + 5ull * 262144), s32, nullptr); // mx
    mel_head_kernel<<<SROWS, 128, 0, stream>>>(s32, melT, out);
}

// Round 4
// 12479.420 us; speedup vs baseline: 1.4693x; 1.0004x over previous
//
#include <hip/hip_runtime.h>
#include <hip/hip_fp16.h>

// ============================================================================
// ATTNAligner forward. R4: lstm_scan weights in NAMED uint4 registers
// (R3's uint4 arrays failed SROA -> scratch -> VGPR_Count=128, 1.86ms/scan).
// Everything else identical to R3.
// ============================================================================

typedef unsigned int u32;
typedef _Float16 h2_t __attribute__((ext_vector_type(2)));
typedef _Float16 f16x8 __attribute__((ext_vector_type(8)));
typedef float f32x4 __attribute__((ext_vector_type(4)));
union U32H2 { u32 u; h2_t h; };

#define T_LEN 1000
#define BATCH 16
#define SROWS (T_LEN * BATCH)

__device__ __forceinline__ float dot2f(u32 a, u32 b, float c) {
#if __has_builtin(__builtin_amdgcn_fdot2)
    U32H2 ua; ua.u = a; U32H2 ub; ub.u = b;
    return __builtin_amdgcn_fdot2(ua.h, ub.h, c, false);
#else
    U32H2 ua; ua.u = a; U32H2 ub; ub.u = b;
    return c + (float)ua.h.x * (float)ub.h.x + (float)ua.h.y * (float)ub.h.y;
#endif
}

__device__ __forceinline__ u32 pack2h(float a, float b) {
    h2_t p; p.x = (_Float16)a; p.y = (_Float16)b;
    U32H2 u; u.h = p; return u.u;
}

__device__ __forceinline__ float fsigm(float x) { return 1.0f / (1.0f + __expf(-x)); }
__device__ __forceinline__ float ftanh_(float x) {
    x = fminf(fmaxf(x, -15.0f), 15.0f);
    float e = __expf(-2.0f * x);
    return (1.0f - e) / (1.0f + e);
}

// ---------------------------------------------------------------------------
// Generic transpose: src[R][C] -> dst[C][R]  (fp32; ctc/mel head weights)
// ---------------------------------------------------------------------------
__global__ void transpose_kernel(const float* __restrict__ src, float* __restrict__ dst,
                                 int R, int C) {
    int total = R * C;
    for (int i = blockIdx.x * blockDim.x + threadIdx.x; i < total; i += gridDim.x * blockDim.x) {
        int r = i / C, c = i - r * C;
        dst[(size_t)c * R + r] = src[i];
    }
}

// ---------------------------------------------------------------------------
// Pack recurrent weights Whh [layers][2][1024][256] f32
//   -> wp [layers][2][32 g][1024 j][4 q] u32, u32 = half2(W[j][8g+2q], W[j][8g+2q+1])
// ---------------------------------------------------------------------------
__global__ void prep_whh_kernel(const float* __restrict__ whh, u32* __restrict__ wp, int total) {
    for (int idx = blockIdx.x * blockDim.x + threadIdx.x; idx < total; idx += gridDim.x * blockDim.x) {
        int q = idx & 3;
        int j = (idx >> 2) & 1023;
        int g = (idx >> 12) & 31;
        int d = (idx >> 17) & 1;
        int l = idx >> 18;
        int k = g * 8 + q * 2;
        const float* s = whh + ((size_t)(l * 2 + d) * 1024 + j) * 256 + k;
        wp[idx] = pack2h(s[0], s[1]);
    }
}

// ---------------------------------------------------------------------------
// Pack a weight matrix into MFMA-16x16x32 B-fragment order (fp16).
// Logical B[k][n] = src[n*sn + k*sk + off] (fp32).
// dst layout: [nt = n/16][ks = k/32][lane 64][i 8],
//   n = nt*16 + (lane&15), k = ks*32 + (lane>>4)*8 + i.
// ---------------------------------------------------------------------------
__global__ void pack_b_kernel(const float* __restrict__ src, _Float16* __restrict__ dst,
                              int N, int K, int sn, int sk, int off) {
    int total = N * K;
    int kst = K >> 5;
    for (int idx = blockIdx.x * blockDim.x + threadIdx.x; idx < total; idx += gridDim.x * blockDim.x) {
        int i = idx & 7;
        int lane = (idx >> 3) & 63;
        int rest = idx >> 9;
        int ks = rest % kst;
        int nt = rest / kst;
        int n = nt * 16 + (lane & 15);
        int k = ks * 32 + (lane >> 4) * 8 + i;
        dst[idx] = (_Float16)src[(size_t)n * sn + (size_t)k * sk + off];
    }
}

// ---------------------------------------------------------------------------
// Conv1: mels [B][80][T] (normalized inline) -> y1 [B][512][T] fp32, K=5 + BN
// ---------------------------------------------------------------------------
__global__ __launch_bounds__(256) void conv1_kernel(
    const float* __restrict__ mels, const float* __restrict__ w,
    const float* __restrict__ cbias, const float* __restrict__ bg,
    const float* __restrict__ bb, const float* __restrict__ bm,
    const float* __restrict__ bv, float* __restrict__ y1)
{
    __shared__ float xin[80 * 72];
    int t0 = blockIdx.x * 64;
    int b = blockIdx.y;
    int tid = threadIdx.x;
    for (int idx = tid; idx < 80 * 68; idx += 256) {
        int m = idx / 68, i = idx - m * 68;
        int t = t0 - 4 + i;
        float v = 0.0f;
        if (t >= 0 && t < T_LEN) v = mels[(size_t)(b * 80 + m) * T_LEN + t] * (1.0f / 6.0f) + 1.0f;
        xin[m * 72 + i] = v;
    }
    __syncthreads();
    int tg = tid & 15, cl = tid >> 4;
    for (int pass = 0; pass < 32; ++pass) {
        int c = pass * 16 + cl;
        const float* wc = w + (size_t)c * 400;
        float a0 = 0, a1 = 0, a2 = 0, a3 = 0;
        for (int m = 0; m < 80; ++m) {
            float4 xa = *(const float4*)&xin[m * 72 + tg * 4];
            float4 xb = *(const float4*)&xin[m * 72 + tg * 4 + 4];
            float w0 = wc[m * 5 + 0], w1 = wc[m * 5 + 1], w2 = wc[m * 5 + 2];
            float w3 = wc[m * 5 + 3], w4 = wc[m * 5 + 4];
            a0 += w0 * xa.x + w1 * xa.y + w2 * xa.z + w3 * xa.w + w4 * xb.x;
            a1 += w0 * xa.y + w1 * xa.z + w2 * xa.w + w3 * xb.x + w4 * xb.y;
            a2 += w0 * xa.z + w1 * xa.w + w2 * xb.x + w3 * xb.y + w4 * xb.z;
            a3 += w0 * xa.w + w1 * xb.x + w2 * xb.y + w3 * xb.z + w4 * xb.w;
        }
        float scale = bg[c] * rsqrtf(bv[c] + 1e-5f);
        float shift = (cbias[c] - bm[c]) * scale + bb[c];
        int tb = t0 + tg * 4;
        float* yp = y1 + (size_t)(b * 512 + c) * T_LEN + tb;
        if (tb + 0 < T_LEN) yp[0] = a0 * scale + shift;
        if (tb + 1 < T_LEN) yp[1] = a1 * scale + shift;
        if (tb + 2 < T_LEN) yp[2] = a2 * scale + shift;
        if (tb + 3 < T_LEN) yp[3] = a3 * scale + shift;
    }
}

// ---------------------------------------------------------------------------
// Relayout conv1 output: y1 [B][512][T] fp32 -> f0 [(t*16+b)][512] fp16
// ---------------------------------------------------------------------------
__global__ __launch_bounds__(256) void relayout_kernel(
    const float* __restrict__ y1, _Float16* __restrict__ dst)
{
    __shared__ float tile[64][65];
    int t0 = blockIdx.x * 64;
    int c0 = blockIdx.y * 64;
    int b = blockIdx.z;
    int tid = threadIdx.x;
#pragma unroll
    for (int q = 0; q < 16; ++q) {
        int lin = tid + q * 256;
        int cl = lin >> 6, tl = lin & 63;
        int t = t0 + tl;
        tile[cl][tl] = (t < T_LEN) ? y1[(size_t)(b * 512 + c0 + cl) * T_LEN + t] : 0.0f;
    }
    __syncthreads();
#pragma unroll
    for (int q = 0; q < 16; ++q) {
        int lin = tid + q * 256;
        int rl = lin >> 6, cc = lin & 63;
        int t = t0 + rl;
        if (t < T_LEN)
            dst[(size_t)(t * BATCH + b) * 512 + c0 + cc] = (_Float16)tile[cc][rl];
    }
}

// ---------------------------------------------------------------------------
// MFMA fp16 GEMM. C[M=16000][N] = A[M][K] @ Bpack (+ bias / BN epilogue).
// MODE 0: A fp16 [M][K1] (+A2 concat), C fp32 (+bias).
// MODE 1: conv2 — A = f0 [M][512], 5 k-phases, row shift (kph-4)*16;
//         C fp16 with BatchNorm folded.
// ---------------------------------------------------------------------------
template<int MODE>
__global__ __launch_bounds__(512, 2) void gemm_mfma(
    const _Float16* __restrict__ A, const _Float16* __restrict__ A2, int K1,
    const uint4* __restrict__ Bp, const float* __restrict__ bias,
    float* __restrict__ C32, _Float16* __restrict__ C16,
    const float* __restrict__ cvb, const float* __restrict__ bg,
    const float* __restrict__ bb, const float* __restrict__ bm,
    const float* __restrict__ bv, int N, int K)
{
    __shared__ _Float16 At[128 * 40];
    const int m0 = blockIdx.x * 128, n0 = blockIdx.y * 128;
    const int tid = threadIdx.x, lane = tid & 63, w = tid >> 6;
    const int wm = w >> 2, wn = w & 3;
    const int srow = tid >> 2, sseg = tid & 3;
    const int ksteps = K >> 5;
    f32x4 acc[4][2];
#pragma unroll
    for (int i = 0; i < 4; ++i) { acc[i][0] = (f32x4)0.0f; acc[i][1] = (f32x4)0.0f; }

    for (int ks = 0; ks < ksteps; ++ks) {
        int k0 = ks << 5;
        uint4 av;
        if (MODE == 1) {
            int kph = k0 >> 9, kk = k0 & 511;
            int rsrc = m0 + srow + (kph - 4) * 16;
            if (rsrc >= 0) av = *(const uint4*)(A + (size_t)rsrc * 512 + kk + sseg * 8);
            else { av.x = av.y = av.z = av.w = 0u; }
        } else {
            int col = k0 + sseg * 8;
            const _Float16* src = (col < K1) ? (A + (size_t)(m0 + srow) * K1 + col)
                                             : (A2 + (size_t)(m0 + srow) * (K - K1) + (col - K1));
            av = *(const uint4*)src;
        }
        __syncthreads();
        *(uint4*)&At[srow * 40 + sseg * 8] = av;
        __syncthreads();

        f16x8 bf[2];
#pragma unroll
        for (int ct = 0; ct < 2; ++ct) {
            int nt = (n0 >> 4) + wn * 2 + ct;
            int bblk = (MODE == 1) ? ((ks >> 4) * 512 + nt * 16 + (ks & 15))
                                   : (nt * ksteps + ks);
            uint4 braw = Bp[(size_t)bblk * 64 + lane];
            bf[ct] = *(f16x8*)&braw;
        }
#pragma unroll
        for (int rt = 0; rt < 4; ++rt) {
            f16x8 af = *(f16x8*)&At[(wm * 64 + rt * 16 + (lane & 15)) * 40 + (lane >> 4) * 8];
            acc[rt][0] = __builtin_amdgcn_mfma_f32_16x16x32_f16(af, bf[0], acc[rt][0], 0, 0, 0);
            acc[rt][1] = __builtin_amdgcn_mfma_f32_16x16x32_f16(af, bf[1], acc[rt][1], 0, 0, 0);
        }
    }

    const int r0 = m0 + wm * 64 + (lane >> 4) * 4;
    const int cb0 = n0 + wn * 32 + (lane & 15);
#pragma unroll
    for (int ct = 0; ct < 2; ++ct) {
        int col = cb0 + ct * 16;
        float badd = 0.0f, sc = 0.0f, sh = 0.0f;
        if (MODE == 0) { if (bias) badd = bias[col]; }
        else {
            sc = bg[col] * rsqrtf(bv[col] + 1e-5f);
            sh = (cvb[col] - bm[col]) * sc + bb[col];
        }
#pragma unroll
        for (int rt = 0; rt < 4; ++rt) {
#pragma unroll
            for (int rr = 0; rr < 4; ++rr) {
                int row = r0 + rt * 16 + rr;
                float v = acc[rt][ct][rr];
                if (MODE == 0) C32[(size_t)row * N + col] = v + badd;
                else           C16[(size_t)row * 512 + col] = (_Float16)(v * sc + sh);
            }
        }
    }
}

// ---------------------------------------------------------------------------
// LSTM scan (R4): one block per (batch, dir), 512 threads, 2 columns each.
// Weight groups g0..31 (uint4 per column): g0..8 in LDS (147KB),
// g9..29 in 42 NAMED uint4 registers (no arrays -> guaranteed SROA),
// g30..31 streamed from L2 each step.
// ---------------------------------------------------------------------------
#define SCAN_LDS (147456 + 4096 + 512)

#define G21(M) M(0) M(1) M(2) M(3) M(4) M(5) M(6) M(7) M(8) M(9) M(10) \
  M(11) M(12) M(13) M(14) M(15) M(16) M(17) M(18) M(19) M(20)

__global__ __launch_bounds__(512, 2) void lstm_scan(
    const float* __restrict__ pre, const uint4* __restrict__ WPl,
    float* __restrict__ out32, _Float16* __restrict__ out16)
{
    const int b = blockIdx.x >> 1;
    const int dir = blockIdx.x & 1;
    const int tid = threadIdx.x;
    const int j0 = tid, j1 = tid + 512;

    extern __shared__ char smem[];
    uint4* w_lds = (uint4*)smem;                    // [9*1024]
    float* gates = (float*)(smem + 147456);         // [1024]
    u32* h16 = (u32*)(smem + 147456 + 4096);        // [128]

    const uint4* wp = WPl + (size_t)dir * 32768;

    for (int i = tid; i < 9216; i += 512) w_lds[i] = wp[i];

    // 42 named uint4 register-resident weight groups (g9..g29, both columns)
#define DECLW(n) uint4 wa##n = wp[(9 + n) * 1024 + j0]; \
                 uint4 wb##n = wp[(9 + n) * 1024 + j1];
    G21(DECLW)
#undef DECLW

    if (tid < 128) h16[tid] = 0u;
    float c = 0.0f;
    __syncthreads();

    for (int step = 0; step < T_LEN; ++step) {
        int tt = dir ? (T_LEN - 1 - step) : step;
        const float* prow = pre + (size_t)(tt * BATCH + b) * 2048 + (dir << 10);
        float acc0 = prow[j0];
        float acc1 = prow[j1];
        // streamed groups 30,31 (prefetch; 32KB/step/block, L2-shared by dir)
        uint4 sa0 = wp[30 * 1024 + j0], sb0 = wp[30 * 1024 + j1];
        uint4 sa1 = wp[31 * 1024 + j0], sb1 = wp[31 * 1024 + j1];
#pragma unroll
        for (int g = 0; g < 9; ++g) {
            uint4 hv = *(const uint4*)&h16[g * 4];
            uint4 w0 = w_lds[g * 1024 + j0];
            uint4 w1 = w_lds[g * 1024 + j1];
            acc0 = dot2f(hv.x, w0.x, acc0); acc0 = dot2f(hv.y, w0.y, acc0);
            acc0 = dot2f(hv.z, w0.z, acc0); acc0 = dot2f(hv.w, w0.w, acc0);
            acc1 = dot2f(hv.x, w1.x, acc1); acc1 = dot2f(hv.y, w1.y, acc1);
            acc1 = dot2f(hv.z, w1.z, acc1); acc1 = dot2f(hv.w, w1.w, acc1);
        }
#define USEW(n) { uint4 hv = *(const uint4*)&h16[(9 + n) * 4]; \
        acc0 = dot2f(hv.x, wa##n.x, acc0); acc0 = dot2f(hv.y, wa##n.y, acc0); \
        acc0 = dot2f(hv.z, wa##n.z, acc0); acc0 = dot2f(hv.w, wa##n.w, acc0); \
        acc1 = dot2f(hv.x, wb##n.x, acc1); acc1 = dot2f(hv.y, wb##n.y, acc1); \
        acc1 = dot2f(hv.z, wb##n.z, acc1); acc1 = dot2f(hv.w, wb##n.w, acc1); }
        G21(USEW)
#undef USEW
        {
            uint4 hv = *(const uint4*)&h16[30 * 4];
            acc0 = dot2f(hv.x, sa0.x, acc0); acc0 = dot2f(hv.y, sa0.y, acc0);
            acc0 = dot2f(hv.z, sa0.z, acc0); acc0 = dot2f(hv.w, sa0.w, acc0);
            acc1 = dot2f(hv.x, sb0.x, acc1); acc1 = dot2f(hv.y, sb0.y, acc1);
            acc1 = dot2f(hv.z, sb0.z, acc1); acc1 = dot2f(hv.w, sb0.w, acc1);
        }
        {
            uint4 hv = *(const uint4*)&h16[31 * 4];
            acc0 = dot2f(hv.x, sa1.x, acc0); acc0 = dot2f(hv.y, sa1.y, acc0);
            acc0 = dot2f(hv.z, sa1.z, acc0); acc0 = dot2f(hv.w, sa1.w, acc0);
            acc1 = dot2f(hv.x, sb1.x, acc1); acc1 = dot2f(hv.y, sb1.y, acc1);
            acc1 = dot2f(hv.z, sb1.z, acc1); acc1 = dot2f(hv.w, sb1.w, acc1);
        }
        gates[j0] = acc0;
        gates[j1] = acc1;
        __syncthreads();
        if (tid < 256) {
            float gi = gates[tid], gf = gates[tid + 256];
            float gg = gates[tid + 512], go = gates[tid + 768];
            c = fsigm(gf) * c + fsigm(gi) * ftanh_(gg);
            float h = fsigm(go) * ftanh_(c);
            size_t orow = (size_t)(tt * BATCH + b) * 512 + dir * 256 + tid;
            if (out32) out32[orow] = h;
            if (out16) out16[orow] = (_Float16)h;
            float hn = __shfl_xor(h, 1);
            if ((tid & 1) == 0) h16[tid >> 1] = pack2h(h, hn);
        }
        __syncthreads();
    }
}

// ---------------------------------------------------------------------------
// LayerNorm over last dim 512, fp32 in -> fp16 out. 256 thr = 4 rows.
// ---------------------------------------------------------------------------
__global__ __launch_bounds__(256) void ln_kernel(
    const float* __restrict__ in, const float* __restrict__ g,
    const float* __restrict__ b, _Float16* __restrict__ out, int rows)
{
    int row = blockIdx.x * 4 + (threadIdx.x >> 6);
    if (row >= rows) return;
    int lane = threadIdx.x & 63;
    const float4* x = (const float4*)(in + (size_t)row * 512);
    float4 v0 = x[lane * 2], v1 = x[lane * 2 + 1];
    float s = v0.x + v0.y + v0.z + v0.w + v1.x + v1.y + v1.z + v1.w;
    float sq = v0.x * v0.x + v0.y * v0.y + v0.z * v0.z + v0.w * v0.w
             + v1.x * v1.x + v1.y * v1.y + v1.z * v1.z + v1.w * v1.w;
#pragma unroll
    for (int m = 1; m < 64; m <<= 1) {
        s += __shfl_xor(s, m);
        sq += __shfl_xor(sq, m);
    }
    float mu = s * (1.0f / 512.0f);
    float var = sq * (1.0f / 512.0f) - mu * mu;
    float rs = rsqrtf(var + 1e-5f);
    const float4* g4 = (const float4*)g;
    const float4* b4 = (const float4*)b;
    f16x8 r;
    float vv[8] = {v0.x, v0.y, v0.z, v0.w, v1.x, v1.y, v1.z, v1.w};
    float4 gg0 = g4[lane * 2], gg1 = g4[lane * 2 + 1];
    float4 bb0 = b4[lane * 2], bb1 = b4[lane * 2 + 1];
    float gA[8] = {gg0.x, gg0.y, gg0.z, gg0.w, gg1.x, gg1.y, gg1.z, gg1.w};
    float bA[8] = {bb0.x, bb0.y, bb0.z, bb0.w, bb1.x, bb1.y, bb1.z, bb1.w};
#pragma unroll
    for (int q = 0; q < 8; ++q) r[q] = (_Float16)((vv[q] - mu) * rs * gA[q] + bA[q]);
    *(f16x8*)&out[(size_t)row * 512 + lane * 8] = r;
}

// ---------------------------------------------------------------------------
// CTC head: log_softmax(relu(cx) @ ctcWt) * mask. One block (128 thr) per row.
// ---------------------------------------------------------------------------
__global__ __launch_bounds__(128) void ctc_head_kernel(
    const float* __restrict__ cx, const float* __restrict__ ctcWt,
    const int* __restrict__ lens, float* __restrict__ out)
{
    int r = blockIdx.x;
    int t = r / BATCH, b = r - t * BATCH;
    int tid = threadIdx.x;
    __shared__ float xr[512];
    __shared__ float red[128];
    for (int i = tid; i < 512; i += 128) xr[i] = fmaxf(cx[(size_t)r * 512 + i], 0.0f);
    __syncthreads();
    float logit = 0.0f;
    if (tid < 80) {
#pragma unroll 8
        for (int k = 0; k < 512; ++k) logit += xr[k] * ctcWt[k * 80 + tid];
    }
    red[tid] = (tid < 80) ? logit : -1e30f;
    __syncthreads();
    for (int off = 64; off > 0; off >>= 1) {
        if (tid < off) red[tid] = fmaxf(red[tid], red[tid + off]);
        __syncthreads();
    }
    float m = red[0];
    __syncthreads();
    red[tid] = (tid < 80) ? __expf(logit - m) : 0.0f;
    __syncthreads();
    for (int off = 64; off > 0; off >>= 1) {
        if (tid < off) red[tid] += red[tid + off];
        __syncthreads();
    }
    float lsum = __logf(red[0]);
    if (tid < 80) {
        float lp = logit - m - lsum;
        out[(size_t)r * 80 + tid] = (t < lens[b]) ? lp : 0.0f;
    }
}

// ---------------------------------------------------------------------------
// Mel head: (mx @ melWt) * 6 - 6. One block (128 thr) per row.
// ---------------------------------------------------------------------------
__global__ __launch_bounds__(128) void mel_head_kernel(
    const float* __restrict__ mx, const float* __restrict__ melWt,
    float* __restrict__ out)
{
    int r = blockIdx.x;
    int tid = threadIdx.x;
    __shared__ float xr[512];
    for (int i = tid; i < 512; i += 128) xr[i] = mx[(size_t)r * 512 + i];
    __syncthreads();
    if (tid < 80) {
        float acc = 0.0f;
#pragma unroll 8
        for (int k = 0; k < 512; ++k) acc += xr[k] * melWt[k * 80 + tid];
        out[(size_t)r * 80 + tid] = acc * 6.0f - 6.0f;
    }
}

// ===========================================================================
extern "C" void kernel_launch(void* const* d_in, const int* in_sizes, int n_in,
                              void* d_out, int out_size, void* d_ws, size_t ws_size,
                              hipStream_t stream) {
    const float* mels = (const float*)d_in[0];
    const float* c1w = (const float*)d_in[1];
    const float* c1b = (const float*)d_in[2];
    const float* bn1g = (const float*)d_in[3];
    const float* bn1b = (const float*)d_in[4];
    const float* bn1m = (const float*)d_in[5];
    const float* bn1v = (const float*)d_in[6];
    const float* c2w = (const float*)d_in[7];
    const float* c2b = (const float*)d_in[8];
    const float* bn2g = (const float*)d_in[9];
    const float* bn2b = (const float*)d_in[10];
    const float* bn2m = (const float*)d_in[11];
    const float* bn2v = (const float*)d_in[12];
    const float* eWih = (const float*)d_in[13];
    const float* eWhh = (const float*)d_in[14];
    const float* eb   = (const float*)d_in[15];
    const float* elng = (const float*)d_in[16];
    const float* elnb = (const float*)d_in[17];
    const float* cWih = (const float*)d_in[18];
    const float* cWhh = (const float*)d_in[19];
    const float* cb   = (const float*)d_in[20];
    const float* ctcW = (const float*)d_in[21];
    const float* btlW = (const float*)d_in[22];
    const float* lng  = (const float*)d_in[23];
    const float* lnb  = (const float*)d_in[24];
    const float* dWih = (const float*)d_in[25];
    const float* dWhh = (const float*)d_in[26];
    const float* db   = (const float*)d_in[27];
    const float* melW = (const float*)d_in[28];
    const int* mel_lengths = (const int*)d_in[29];

    float* out = (float*)d_out;          // [SROWS*80 mel][SROWS*80 logprob]
    float* ws = (float*)d_ws;

    // ---- workspace layout ----
    float* preB = ws;                                   // 32,768,000 f32
    float* s32  = ws + 32768000;                        //  8,192,000 f32
    _Float16* f0 = (_Float16*)(ws + 40960000);          //  8,192,000 f16 each
    _Float16* f1 = f0 + 8192000;
    _Float16* f2 = f1 + 8192000;
    _Float16* f3 = f2 + 8192000;
    _Float16* BP    = f3 + 8192000;                     // 6 x 1,048,576 f16
    _Float16* BPbtl = BP + 6ull * 1048576;              // 524,288 f16
    _Float16* BPcv  = BPbtl + 524288;                   // 5 x 262,144 f16
    u32* wpAll = (u32*)(BPcv + 5ull * 262144);          // 6 x 262,144 u32
    float* ctcT = (float*)(wpAll + 6ull * 262144);      // 40,960 f32
    float* melT = ctcT + 40960;                         // 40,960 f32

    (void)hipFuncSetAttribute((const void*)lstm_scan,
                              hipFuncAttributeMaxDynamicSharedMemorySize, SCAN_LDS);

    // ---- weight prep ----
    transpose_kernel<<<160, 256, 0, stream>>>(ctcW, ctcT, 80, 512);
    transpose_kernel<<<160, 256, 0, stream>>>(melW, melT, 80, 512);
    prep_whh_kernel<<<2048, 256, 0, stream>>>(eWhh, wpAll + 0ull * 262144, 2 * 262144);
    prep_whh_kernel<<<2048, 256, 0, stream>>>(cWhh, wpAll + 2ull * 262144, 2 * 262144);
    prep_whh_kernel<<<2048, 256, 0, stream>>>(dWhh, wpAll + 4ull * 262144, 2 * 262144);
    for (int l = 0; l < 2; ++l) {
        pack_b_kernel<<<1024, 256, 0, stream>>>(eWih + (size_t)l * 1048576,
                                                BP + (size_t)(0 + l) * 1048576, 2048, 512, 512, 1, 0);
        pack_b_kernel<<<1024, 256, 0, stream>>>(cWih + (size_t)l * 1048576,
                                                BP + (size_t)(2 + l) * 1048576, 2048, 512, 512, 1, 0);
        pack_b_kernel<<<1024, 256, 0, stream>>>(dWih + (size_t)l * 1048576,
                                                BP + (size_t)(4 + l) * 1048576, 2048, 512, 512, 1, 0);
    }
    pack_b_kernel<<<1024, 256, 0, stream>>>(btlW, BPbtl, 512, 1024, 1024, 1, 0);
    for (int kph = 0; kph < 5; ++kph)
        pack_b_kernel<<<512, 256, 0, stream>>>(c2w, BPcv + (size_t)kph * 262144,
                                               512, 512, 2560, 5, kph);

    // ---- prenet ----
    conv1_kernel<<<dim3(16, 16), 256, 0, stream>>>(mels, c1w, c1b, bn1g, bn1b, bn1m, bn1v, s32);
    relayout_kernel<<<dim3(16, 8, 16), 256, 0, stream>>>(s32, f0);
    gemm_mfma<1><<<dim3(125, 4), 512, 0, stream>>>(f0, nullptr, 0, (const uint4*)BPcv, nullptr,
                                                   nullptr, f1, c2b, bn2g, bn2b, bn2m, bn2v, 512, 2560);

    dim3 gN2048(125, 16), gN512(125, 4);
    const uint4* BPu = (const uint4*)BP;
    // ---- encoder ----
    gemm_mfma<0><<<gN2048, 512, 0, stream>>>(f1, nullptr, 512, BPu + 0ull * 131072, eb,
                                             preB, nullptr, nullptr, nullptr, nullptr, nullptr, nullptr, 2048, 512);
    lstm_scan<<<32, 512, SCAN_LDS, stream>>>(preB, (const uint4*)(wpAll + 0ull * 262144), nullptr, f2);
    gemm_mfma<0><<<gN2048, 512, 0, stream>>>(f2, nullptr, 512, BPu + 1ull * 131072, eb + 2048,
                                             preB, nullptr, nullptr, nullptr, nullptr, nullptr, nullptr, 2048, 512);
    lstm_scan<<<32, 512, SCAN_LDS, stream>>>(preB, (const uint4*)(wpAll + 1ull * 262144), s32, nullptr);
    ln_kernel<<<4000, 256, 0, stream>>>(s32, elng, elnb, f2, SROWS);   // f2 = h (fp16)
    // ---- ctc decoder ----
    gemm_mfma<0><<<gN2048, 512, 0, stream>>>(f2, nullptr, 512, BPu + 2ull * 131072, cb,
                                             preB, nullptr, nullptr, nullptr, nullptr, nullptr, nullptr, 2048, 512);
    lstm_scan<<<32, 512, SCAN_LDS, stream>>>(preB, (const uint4*)(wpAll + 2ull * 262144), nullptr, f3);
    gemm_mfma<0><<<gN2048, 512, 0, stream>>>(f3, nullptr, 512, BPu + 3ull * 131072, cb + 2048,
                                             preB, nullptr, nullptr, nullptr, nullptr, nullptr, nullptr, 2048, 512);
    lstm_scan<<<32, 512, SCAN_LDS, stream>>>(preB, (const uint4*)(wpAll + 3ull * 262144), s32, f1); // cx
    ctc_head_kernel<<<SROWS, 128, 0, stream>>>(s32, ctcT, mel_lengths, out + (size_t)SROWS * 80);
    // ---- bottleneck: [h | cx] @ btlW.T -> LN ----
    gemm_mfma<0><<<gN512, 512, 0, stream>>>(f2, f1, 512, (const uint4*)BPbtl, nullptr,
                                            preB, nullptr, nullptr, nullptr, nullptr, nullptr, nullptr, 512, 1024);
    ln_kernel<<<4000, 256, 0, stream>>>(preB, lng, lnb, f3, SROWS);    // f3 = bottleneck (fp16)
    // ---- mel decoder ----
    gemm_mfma<0><<<gN2048, 512, 0, stream>>>(f3, nullptr, 512, BPu + 4ull * 131072, db,
                                             preB, nullptr, nullptr, nullptr, nullptr, nullptr, nullptr, 2048, 512);
    lstm_scan<<<32, 512, SCAN_LDS, stream>>>(preB, (const uint4*)(wpAll + 4ull * 262144), nullptr, f2);
    gemm_mfma<0><<<gN2048, 512, 0, stream>>>(f2, nullptr, 512, BPu + 5ull * 131072, db + 2048,
                                             preB, nullptr, nullptr, nullptr, nullptr, nullptr, nullptr, 2048, 512);
    lstm_scan<<<32, 512, SCAN_LDS, stream>>>(preB, (const uint4*)(wpAll + 5ull * 262144), s32, nullptr); // mx
    mel_head_kernel<<<SROWS, 128, 0, stream>>>(s32, melT, out);
}